// Round 15
// baseline (956.593 us; speedup 1.0000x reference)
//
#include <hip/hip_runtime.h>
#include <math.h>

#define T_SEQ   1024
#define BATCH   2
#define CDIM    1024
#define NHEAD   16
#define VHEAD   32
#define KEEP    256
#define HEAD_D  96   // NOPE + ROPE
#define SCALE_ATTN 0.1020620726159658f  // 1/sqrt(96)

// flash tile params (v5, measured-best: 384 us)
#define BQ   64
#define BKT  64
#define SK   100    // Q/K LDS row stride: 100%32=4 -> <=2-way on b128 (free)
#define SPT  66     // Pt row stride [k][q]: even -> aligned b64 columns
#define SPV  36     // V LDS row stride

// GEMM tile params: 128x128 block, 8x8 micro, single LDS buffer + reg prefetch
#define GBK 16
#define SA  132     // padded row stride: 132%32=4 -> <=2-way (free)

// XW layout: x @ [cq | ckv | krope | wink | winv | imp | gate]
#define XWW    2244
#define C_CQ   0      // 96
#define C_CKV  96     // 32
#define C_KRO  128    // 64
#define C_WINK 192    // 1536 (16 heads x 96)
#define C_WINV 1728   // 512  (16 heads x 32)
#define C_IMP  2240   // 1
#define C_GATE 2241   // 3

// QKV layout: [nq|ckv] @ blockdiag -> [qn | qr | kn | v1]
#define QKVW   2560
#define C_QN   0      // 512
#define C_QR   512    // 1024 (UN-roped; rope folded into flash Q staging)
#define C_KN   1536   // 512
#define C_V1   2048   // 512

#define SKW  2048   // skv: [0:1536) ks | [1536:2048) vs  (roped by rope_tab)

// ---------------------------------------------------------------------------
// fp32 GEMM v5: C[M,N] = A[M,K] @ B[K,N], strides lda/ldb/ldc.
// 128x128 block, 256 threads, 8x8 micro-tile, single LDS buffer,
// register-prefetch software pipeline (next tile's global loads issue under
// current tile's FMAs; ~110 VGPR budget, under the 128 cliff).
// Split-K via blockIdx.z (gridDim.z>1 -> atomicAdd, C zeroed) — profitable
// only for small outputs (round-13 lesson).
// Optional A-row indirection: Arowidx!=nullptr -> A row gr reads source row
// (gr/rowdiv)*rowmul + Arowidx[gr]  (hoisted to registers before K-loop).
// ---------------------------------------------------------------------------
__global__ __launch_bounds__(256) void gemm128(const float* __restrict__ A,
                                               const float* __restrict__ B,
                                               float* __restrict__ C,
                                               int M, int N, int K,
                                               int lda, int ldb, int ldc,
                                               int kchunk,
                                               const int* __restrict__ Arowidx,
                                               int rowdiv, int rowmul) {
    __shared__ float As[GBK][SA];   // [k][m] transposed A tile
    __shared__ float Bs[GBK][SA];   // [k][n]
    int t = threadIdx.x;
    int tx = t & 15, ty = t >> 4;
    int row0 = blockIdx.y * 128, col0 = blockIdx.x * 128;
    int kb = blockIdx.z * kchunk;
    int ke = min(K, kb + kchunk);
    float acc[8][8] = {};

    // staging coordinates (fixed across K-steps)
    const int arow = t >> 2;        // A rows arow, arow+64
    const int ak4  = t & 3;         // A k-quad
    const int bkk  = t >> 5;        // B k rows bkk, bkk+8
    const int bn4  = t & 31;        // B col quad
    const int gcB  = col0 + bn4 * 4;

    // hoist A source rows
    int asrc[2]; bool aok[2];
#pragma unroll
    for (int r = 0; r < 2; r++) {
        int gr = row0 + arow + 64 * r;
        aok[r] = (gr < M);
        int ar = gr;
        if (Arowidx != nullptr && aok[r]) ar = (gr / rowdiv) * rowmul + Arowidx[gr];
        asrc[r] = ar;
    }

    float4 pa[2], pb[2];
    // prologue: prefetch first k-step
    {
        int k0 = kb;
#pragma unroll
        for (int r = 0; r < 2; r++) {
            pa[r] = make_float4(0.f, 0.f, 0.f, 0.f);
            if (aok[r]) pa[r] = *(const float4*)&A[(size_t)asrc[r] * lda + k0 + ak4 * 4];
            pb[r] = make_float4(0.f, 0.f, 0.f, 0.f);
            if (gcB + 3 < N) {
                pb[r] = *(const float4*)&B[(size_t)(k0 + bkk + 8 * r) * ldb + gcB];
            } else if (gcB < N) {
                const float* bp = &B[(size_t)(k0 + bkk + 8 * r) * ldb];
                float tmp[4] = {0.f, 0.f, 0.f, 0.f};
                for (int j = 0; j < 4 && gcB + j < N; j++) tmp[j] = bp[gcB + j];
                pb[r] = make_float4(tmp[0], tmp[1], tmp[2], tmp[3]);
            }
        }
    }

    int nsteps = (ke - kb) / GBK;
    for (int s = 0; s < nsteps; s++) {
        // store prefetched regs to LDS
#pragma unroll
        for (int r = 0; r < 2; r++) {
            As[ak4 * 4 + 0][arow + 64 * r] = pa[r].x;
            As[ak4 * 4 + 1][arow + 64 * r] = pa[r].y;
            As[ak4 * 4 + 2][arow + 64 * r] = pa[r].z;
            As[ak4 * 4 + 3][arow + 64 * r] = pa[r].w;
            *(float4*)&Bs[bkk + 8 * r][bn4 * 4] = pb[r];
        }
        __syncthreads();

        // issue next tile's global loads (latency hides under FMAs below)
        if (s + 1 < nsteps) {
            int kn = kb + (s + 1) * GBK;
#pragma unroll
            for (int r = 0; r < 2; r++) {
                pa[r] = make_float4(0.f, 0.f, 0.f, 0.f);
                if (aok[r]) pa[r] = *(const float4*)&A[(size_t)asrc[r] * lda + kn + ak4 * 4];
                pb[r] = make_float4(0.f, 0.f, 0.f, 0.f);
                if (gcB + 3 < N) {
                    pb[r] = *(const float4*)&B[(size_t)(kn + bkk + 8 * r) * ldb + gcB];
                } else if (gcB < N) {
                    const float* bp = &B[(size_t)(kn + bkk + 8 * r) * ldb];
                    float tmp[4] = {0.f, 0.f, 0.f, 0.f};
                    for (int j = 0; j < 4 && gcB + j < N; j++) tmp[j] = bp[gcB + j];
                    pb[r] = make_float4(tmp[0], tmp[1], tmp[2], tmp[3]);
                }
            }
        }

#pragma unroll
        for (int kk = 0; kk < GBK; kk++) {
            float4 a0 = *(float4*)&As[kk][ty * 4];
            float4 a1 = *(float4*)&As[kk][64 + ty * 4];
            float4 b0 = *(float4*)&Bs[kk][tx * 4];
            float4 b1 = *(float4*)&Bs[kk][64 + tx * 4];
            float av[8] = {a0.x, a0.y, a0.z, a0.w, a1.x, a1.y, a1.z, a1.w};
            float bv[8] = {b0.x, b0.y, b0.z, b0.w, b1.x, b1.y, b1.z, b1.w};
#pragma unroll
            for (int i = 0; i < 8; i++)
#pragma unroll
                for (int j = 0; j < 8; j++) acc[i][j] += av[i] * bv[j];
        }
        __syncthreads();
    }

    bool split = (gridDim.z > 1);
#pragma unroll
    for (int i = 0; i < 8; i++) {
        int gr = row0 + ((i < 4) ? (ty * 4 + i) : (64 + ty * 4 + (i - 4)));
        if (gr >= M) continue;
#pragma unroll
        for (int half = 0; half < 2; half++) {
            int gc = col0 + half * 64 + tx * 4;
            if (gc + 3 >= N) continue;
            float* cp = &C[(size_t)gr * ldc + gc];
            if (split) {
                atomicAdd(cp + 0, acc[i][half * 4 + 0]);
                atomicAdd(cp + 1, acc[i][half * 4 + 1]);
                atomicAdd(cp + 2, acc[i][half * 4 + 2]);
                atomicAdd(cp + 3, acc[i][half * 4 + 3]);
            } else {
                *(float4*)cp = make_float4(acc[i][half * 4 + 0], acc[i][half * 4 + 1],
                                           acc[i][half * 4 + 2], acc[i][half * 4 + 3]);
            }
        }
    }
}

// ---------------------------------------------------------------------------
// merged weight pack + rope table + split-K destination zeroing:
// blocks [0,1024)    -> Bxw rows
//        [1024,1152) -> Bqkv rows
//        [1152,2176) -> Bsel rows
//        [2176,2304) -> tab (cos/sin)
//        [2304,2368) -> zero skv  (split-K dest)
//        [2368,2496) -> zero out  (split-K dest)
__global__ void pack_all(float* __restrict__ Bxw, float* __restrict__ Bqkv,
                         float* __restrict__ Bsel, float2* __restrict__ tab,
                         float* __restrict__ skv, float* __restrict__ outp,
                         const float* __restrict__ cq, const float* __restrict__ ckv,
                         const float* __restrict__ kro, const float* __restrict__ wink,
                         const float* __restrict__ winv, const float* __restrict__ imp,
                         const float* __restrict__ gate,
                         const float* __restrict__ dqn, const float* __restrict__ dqr,
                         const float* __restrict__ dkn, const float* __restrict__ dv,
                         const float* __restrict__ selk, const float* __restrict__ selv) {
    int blk = blockIdx.x;
    if (blk < 1024) {
        int r = blk;
        for (int c = threadIdx.x; c < XWW; c += blockDim.x) {
            float v;
            if      (c < C_CKV)  v = cq  [(size_t)r * 96   + c];
            else if (c < C_KRO)  v = ckv [(size_t)r * 32   + (c - C_CKV)];
            else if (c < C_WINK) v = kro [(size_t)r * 64   + (c - C_KRO)];
            else if (c < C_WINV) v = wink[(size_t)r * 1536 + (c - C_WINK)];
            else if (c < C_IMP)  v = winv[(size_t)r * 512  + (c - C_WINV)];
            else if (c < C_GATE) v = imp [(size_t)r * 1    + (c - C_IMP)];
            else                 v = gate[(size_t)r * 3    + (c - C_GATE)];
            Bxw[(size_t)r * XWW + c] = v;
        }
    } else if (blk < 1152) {
        int r = blk - 1024;
        for (int c = threadIdx.x; c < QKVW; c += blockDim.x) {
            float v = 0.f;
            if (r < 96) {
                if (c < C_QR)      v = dqn[(size_t)r * 512 + c];
                else if (c < C_KN) v = dqr[(size_t)r * 1024 + (c - C_QR)];
            } else {
                if (c >= C_KN && c < C_V1) v = dkn[(size_t)(r - 96) * 512 + (c - C_KN)];
                else if (c >= C_V1)        v = dv [(size_t)(r - 96) * 512 + (c - C_V1)];
            }
            Bqkv[(size_t)r * QKVW + c] = v;
        }
    } else if (blk < 2176) {
        int r = blk - 1152;
        for (int c = threadIdx.x; c < SKW; c += blockDim.x) {
            float v = (c < 1536) ? selk[(size_t)r * 1536 + c]
                                 : selv[(size_t)r * 512 + (c - 1536)];
            Bsel[(size_t)r * SKW + c] = v;
        }
    } else if (blk < 2304) {
        int idx = (blk - 2176) * 256 + threadIdx.x;   // 128 x 256 = 32768
        if (idx < T_SEQ * 32) {
            int pos = idx >> 5, i = idx & 31;
            float expo = (float)i * (1.0f / 32.0f);
            float f = 1.0f / powf(10000.0f, expo);
            float a = (float)pos * f;
            float s, c;
            sincosf(a, &s, &c);
            tab[idx] = make_float2(c, s);
        }
    } else if (blk < 2368) {
        // zero skv: 512*2048 floats = 262,144 float4 (64 blocks x 256 x 16)
        size_t base = (size_t)(blk - 2304) * 256 + threadIdx.x;
#pragma unroll
        for (int j = 0; j < 16; j++)
            ((float4*)skv)[base + (size_t)j * 16384] = make_float4(0.f, 0.f, 0.f, 0.f);
    } else {
        // zero out: 2048*1024 floats = 524,288 float4 (128 blocks x 256 x 16)
        size_t base = (size_t)(blk - 2368) * 256 + threadIdx.x;
#pragma unroll
        for (int j = 0; j < 16; j++)
            ((float4*)outp)[base + (size_t)j * 32768] = make_float4(0.f, 0.f, 0.f, 0.f);
    }
}

// ---------------------------------------------------------------------------
// fused post-XW row pass: rms(cq), rms(ckv), rope(kro, scale 1/16),
// rope(wink heads). One block per row, 256 threads; disjoint slices.
__global__ void xw_post(float* __restrict__ XW, const float* __restrict__ gq,
                        const float* __restrict__ gkv,
                        const float2* __restrict__ tab) {
    int row = blockIdx.x;
    int t = threadIdx.x;
    int w = t >> 6, lane = t & 63;
    float* rp = XW + (size_t)row * XWW;
    int pos = row & (T_SEQ - 1);
    const float2* tp = tab + pos * 32;

    if (w == 0) {                      // rms over cols [0,96)
        float ss = 0.f;
        for (int d = lane; d < 96; d += 64) { float v = rp[d]; ss += v * v; }
        for (int off = 32; off; off >>= 1) ss += __shfl_xor(ss, off, 64);
        float r = rsqrtf(ss / 96.0f + 1e-6f);
        for (int d = lane; d < 96; d += 64) rp[d] *= r * gq[d];
    } else if (w == 1) {               // rms over cols [96,128)
        float ss = 0.f;
        for (int d = lane; d < 32; d += 64) { float v = rp[C_CKV + d]; ss += v * v; }
        for (int off = 32; off; off >>= 1) ss += __shfl_xor(ss, off, 64);
        float r = rsqrtf(ss / 32.0f + 1e-6f);
        for (int d = lane; d < 32; d += 64) rp[C_CKV + d] *= r * gkv[d];
    } else if (w == 2) {               // rope kro cols [128,192), scale 1/16
        if (lane < 32) {
            float2 cs = tp[lane];
            float v1 = rp[C_KRO + lane], v2 = rp[C_KRO + 32 + lane];
            rp[C_KRO + lane]      = (v1 * cs.x - v2 * cs.y) * (1.0f / NHEAD);
            rp[C_KRO + 32 + lane] = (v1 * cs.y + v2 * cs.x) * (1.0f / NHEAD);
        }
    }
    // wink rope: 16 heads x 32 items, all 256 threads, 2 items each
#pragma unroll
    for (int j = 0; j < 2; j++) {
        int item = t + j * 256;        // 0..511
        int h = item >> 5, i = item & 31;
        float2 cs = tp[i];
        size_t base = (size_t)(C_WINK + 32) + h * 96;
        float v1 = rp[base + i], v2 = rp[base + 32 + i];
        rp[base + i]      = v1 * cs.x - v2 * cs.y;
        rp[base + 32 + i] = v1 * cs.y + v2 * cs.x;
    }
}

// ---------------------------------------------------------------------------
// table-based rope
__global__ void rope_tab(float* __restrict__ buf, int nrows, int rstride,
                         int nheads, int hstride, int roff, int posmod,
                         const float2* __restrict__ tab) {
    int total = nrows * nheads * 32;
    for (int it = blockIdx.x * blockDim.x + threadIdx.x; it < total;
         it += gridDim.x * blockDim.x) {
        int i = it & 31;
        int hr = it >> 5;
        int h = hr % nheads;
        int row = hr / nheads;
        int pos = row % posmod;
        float2 cs = tab[pos * 32 + i];
        size_t base = (size_t)row * rstride + (size_t)h * hstride + roff;
        float v1 = buf[base + i], v2 = buf[base + 32 + i];
        buf[base + i]      = v1 * cs.x - v2 * cs.y;
        buf[base + 32 + i] = v1 * cs.y + v2 * cs.x;
    }
}

// ---------------------------------------------------------------------------
// merged gate softmax + top-k over XW columns; grid = BATCH, 1024 threads
__global__ void topk_gate(const float* __restrict__ xw, int* __restrict__ idx,
                          float* __restrict__ gate) {
    int b = blockIdx.x;
    __shared__ float s[1024];
    __shared__ int ps[1024];
    __shared__ float gred[3][16];
    int t = threadIdx.x;
    const float* rowp = &xw[((size_t)b * T_SEQ + t) * XWW];
    s[t] = rowp[C_IMP];
    float g0 = rowp[C_GATE + 0], g1 = rowp[C_GATE + 1], g2 = rowp[C_GATE + 2];
    for (int off = 32; off; off >>= 1) {
        g0 += __shfl_xor(g0, off, 64);
        g1 += __shfl_xor(g1, off, 64);
        g2 += __shfl_xor(g2, off, 64);
    }
    if ((t & 63) == 0) { int w = t >> 6; gred[0][w] = g0; gred[1][w] = g1; gred[2][w] = g2; }
    __syncthreads();
    if (t == 0) {
        float v0 = 0.f, v1 = 0.f, v2 = 0.f;
        for (int w = 0; w < 16; w++) { v0 += gred[0][w]; v1 += gred[1][w]; v2 += gred[2][w]; }
        v0 /= (float)T_SEQ; v1 /= (float)T_SEQ; v2 /= (float)T_SEQ;
        float m = fmaxf(v0, fmaxf(v1, v2));
        float e0 = expf(v0 - m), e1 = expf(v1 - m), e2 = expf(v2 - m);
        float ssum = e0 + e1 + e2;
        gate[b * 3 + 0] = e0 / ssum;
        gate[b * 3 + 1] = e1 / ssum;
        gate[b * 3 + 2] = e2 / ssum;
    }
    __syncthreads();
    float mine = s[t];
    int rank = 0;
    for (int j = 0; j < 1024; j++) {
        float v = s[j];
        rank += (v > mine) || (v == mine && j < t);
    }
    int selv = (rank < KEEP) ? 1 : 0;
    ps[t] = selv;
    __syncthreads();
    for (int off = 1; off < 1024; off <<= 1) {
        int add = (t >= off) ? ps[t - off] : 0;
        __syncthreads();
        ps[t] += add;
        __syncthreads();
    }
    if (selv) idx[b * KEEP + ps[t] - 1] = t;
}

// ---------------------------------------------------------------------------
// Fused 3-branch flash attention v5 (measured-best) + Q-rope fold
// (once per (row,head), staged by exactly one block).
// Register-resident online softmax; 2 barriers per tile.
// Grid: (T/64, NHEAD, BATCH), 512 threads. LDS 77.3 KB -> 2 blocks/CU.
// ---------------------------------------------------------------------------
__global__ __launch_bounds__(512, 4) void flash_fused(
    const float* __restrict__ qkv, const float* __restrict__ xw,
    const float* __restrict__ skv, const float* __restrict__ gate,
    const float2* __restrict__ tab, float* __restrict__ out) {
    __shared__ float Qs[BQ * SK];
    __shared__ float Ks[BKT * SK];
    __shared__ float Vs[BKT * SPV];
    __shared__ float Pt[BKT * SPT];

    int b = blockIdx.z, h = blockIdx.y;
    int qt = blockIdx.x;
    if (b == 1) qt = (gridDim.x - 1) - qt;   // balance causal cost across z-pairs
    int q0 = qt * BQ;
    int t = threadIdx.x;
    int tq = t >> 4, tk = t & 15;   // S: q=2*tq+i, k=16*j+tk; PV: q=2*tq+i, d=2*tk+j

    // stage Q tile (64 rows x 24 float4); qr rope applied on the fly
    for (int i = t; i < BQ * 24; i += 512) {
        int row = i / 24, d4 = i % 24;
        size_t rq = (size_t)b * T_SEQ + q0 + row;
        float4 v;
        if (d4 < 8) {
            v = *(const float4*)&qkv[rq * QKVW + C_QN + h * 32 + d4 * 4];
        } else {
            const float* qb = &qkv[rq * QKVW + C_QR + h * 64];
            int dd = d4 - 8;                  // 0..15 within 64-wide head slice
            float4 a = *(const float4*)&qb[dd * 4];
            const float2* tp = tab + (size_t)(q0 + row) * 32;
            if (dd < 8) {                     // first half: v1*c - v2*s
                float4 p = *(const float4*)&qb[(dd + 8) * 4];
                int i0 = dd * 4;
                float2 c0 = tp[i0], c1 = tp[i0 + 1], c2 = tp[i0 + 2], c3 = tp[i0 + 3];
                v = make_float4(a.x * c0.x - p.x * c0.y, a.y * c1.x - p.y * c1.y,
                                a.z * c2.x - p.z * c2.y, a.w * c3.x - p.w * c3.y);
            } else {                          // second half: v1*s + v2*c
                float4 p = *(const float4*)&qb[(dd - 8) * 4];
                int i0 = (dd - 8) * 4;
                float2 c0 = tp[i0], c1 = tp[i0 + 1], c2 = tp[i0 + 2], c3 = tp[i0 + 3];
                v = make_float4(p.x * c0.y + a.x * c0.x, p.y * c1.y + a.y * c1.x,
                                p.z * c2.y + a.z * c2.x, p.w * c3.y + a.w * c3.x);
            }
        }
        *(float4*)&Qs[row * SK + d4 * 4] = v;
    }

    int qq0 = q0 + 2 * tq, qq1 = qq0 + 1;
    float comb[2][2] = {};
    for (int phase = 0; phase < 3; phase++) {
        bool causal = (phase != 1);
        int ntiles = causal ? (qt + 1) : (KEEP / BKT);
        float m0 = -1e30f, m1 = -1e30f, l0 = 0.f, l1 = 0.f;
        float o00 = 0.f, o01 = 0.f, o10 = 0.f, o11 = 0.f;

        for (int kt = 0; kt < ntiles; kt++) {
            int j0 = kt * BKT;
            __syncthreads();  // all waves done reading Ks/Vs of prev tile (covers Qs 1st time)

            // stage K tile (64 rows x 24 float4)
            for (int i = t; i < BKT * 24; i += 512) {
                int row = i / 24, d4 = i % 24;
                int j = j0 + row;
                float4 v;
                if (phase == 0) {
                    size_t rk = (size_t)b * T_SEQ + j;
                    if (d4 < 8) v = *(const float4*)&qkv[rk * QKVW + C_KN + h * 32 + d4 * 4];
                    else        v = *(const float4*)&xw[rk * XWW + C_KRO + (d4 - 8) * 4];
                } else if (phase == 1) {
                    v = *(const float4*)&skv[((size_t)b * KEEP + j) * SKW + h * 96 + d4 * 4];
                } else {
                    v = *(const float4*)&xw[((size_t)b * T_SEQ + j) * XWW + C_WINK + h * 96 + d4 * 4];
                }
                *(float4*)&Ks[row * SK + d4 * 4] = v;
            }
            // stage V tile (64 rows x 8 float4)
            for (int i = t; i < BKT * 8; i += 512) {
                int row = i >> 3, d4 = i & 7;
                int j = j0 + row;
                float4 v;
                if (phase == 0)      v = *(const float4*)&qkv[((size_t)b * T_SEQ + j) * QKVW + C_V1 + h * 32 + d4 * 4];
                else if (phase == 1) v = *(const float4*)&skv[((size_t)b * KEEP  + j) * SKW + 1536 + h * 32 + d4 * 4];
                else                 v = *(const float4*)&xw[((size_t)b * T_SEQ + j) * XWW + C_WINV + h * 32 + d4 * 4];
                *(float4*)&Vs[row * SPV + d4 * 4] = v;
            }
            __syncthreads();

            // S = Q.K^T (2q x 4k per thread), registers
            float s0[4] = {}, s1[4] = {};
#pragma unroll 6
            for (int d = 0; d < HEAD_D; d += 4) {
                float4 qa = *(float4*)&Qs[(2 * tq)     * SK + d];
                float4 qb = *(float4*)&Qs[(2 * tq + 1) * SK + d];
#pragma unroll
                for (int j = 0; j < 4; j++) {
                    float4 kv = *(float4*)&Ks[(16 * j + tk) * SK + d];
                    s0[j] += qa.x * kv.x + qa.y * kv.y + qa.z * kv.z + qa.w * kv.w;
                    s1[j] += qb.x * kv.x + qb.y * kv.y + qb.z * kv.z + qb.w * kv.w;
                }
            }
            // scale + mask + tile row-max (in-reg + 4-shfl over 16-lane group)
            float mt0 = -1e30f, mt1 = -1e30f;
#pragma unroll
            for (int j = 0; j < 4; j++) {
                int kk = j0 + 16 * j + tk;
                s0[j] *= SCALE_ATTN;
                s1[j] *= SCALE_ATTN;
                if (causal && kk > qq0) s0[j] = -1e30f;
                if (causal && kk > qq1) s1[j] = -1e30f;
                mt0 = fmaxf(mt0, s0[j]);
                mt1 = fmaxf(mt1, s1[j]);
            }
#pragma unroll
            for (int off = 1; off <= 8; off <<= 1) {
                mt0 = fmaxf(mt0, __shfl_xor(mt0, off, 64));
                mt1 = fmaxf(mt1, __shfl_xor(mt1, off, 64));
            }
            float mn0 = fmaxf(m0, mt0), mn1 = fmaxf(m1, mt1);
            float a0 = __expf(m0 - mn0), a1 = __expf(m1 - mn1);
            m0 = mn0; m1 = mn1;

            // exponentiate in regs, write P once (float2), row-sum via shfl
            float rs0 = 0.f, rs1 = 0.f;
#pragma unroll
            for (int j = 0; j < 4; j++) {
                float p0 = __expf(s0[j] - mn0);
                float p1 = __expf(s1[j] - mn1);
                rs0 += p0; rs1 += p1;
                *(float2*)&Pt[(16 * j + tk) * SPT + 2 * tq] = make_float2(p0, p1);
            }
#pragma unroll
            for (int off = 1; off <= 8; off <<= 1) {
                rs0 += __shfl_xor(rs0, off, 64);
                rs1 += __shfl_xor(rs1, off, 64);
            }
            l0 = l0 * a0 + rs0;
            l1 = l1 * a1 + rs1;

            // PV (2q x 2d). Pt cols 2tq,2tq+1 written by this same wave ->
            // DS in-order per wave, no barrier.
            o00 *= a0; o01 *= a0; o10 *= a1; o11 *= a1;
#pragma unroll 8
            for (int kk = 0; kk < BKT; kk++) {
                float2 pv = *(float2*)&Pt[kk * SPT + 2 * tq];
                float2 vv = *(float2*)&Vs[kk * SPV + 2 * tk];
                o00 += pv.x * vv.x; o01 += pv.x * vv.y;
                o10 += pv.y * vv.x; o11 += pv.y * vv.y;
            }
        }  // key tiles

        // gate combine (m,l in registers, replicated within the group)
        float g = gate[b * 3 + phase];
        float i0 = g / l0, i1 = g / l1;
        comb[0][0] += o00 * i0; comb[0][1] += o01 * i0;
        comb[1][0] += o10 * i1; comb[1][1] += o11 * i1;
    }  // phases

    size_t r0 = ((size_t)b * T_SEQ + q0 + 2 * tq) * 512 + h * 32 + 2 * tk;
    out[r0]           = comb[0][0];
    out[r0 + 1]       = comb[0][1];
    out[r0 + 512]     = comb[1][0];
    out[r0 + 512 + 1] = comb[1][1];
}

// ---------------------------------------------------------------------------
extern "C" void kernel_launch(void* const* d_in, const int* in_sizes, int n_in,
                              void* d_out, int out_size, void* d_ws, size_t ws_size,
                              hipStream_t stream) {
    const float* x        = (const float*)d_in[0];
    const float* w_cq     = (const float*)d_in[1];
    const float* g_qnorm  = (const float*)d_in[2];
    const float* w_dqn    = (const float*)d_in[3];
    const float* w_dqr    = (const float*)d_in[4];
    const float* w_ckv    = (const float*)d_in[5];
    const float* g_kvnorm = (const float*)d_in[6];
    const float* w_dkn    = (const float*)d_in[7];
    const float* w_dv     = (const float*)d_in[8];
    const float* w_krope  = (const float*)d_in[9];
    const float* w_imp    = (const float*)d_in[10];
    const float* w_selk   = (const float*)d_in[11];
    const float* w_selv   = (const float*)d_in[12];
    const float* w_wink   = (const float*)d_in[13];
    const float* w_winv   = (const float*)d_in[14];
    const float* w_gate   = (const float*)d_in[15];
    const float* w_proj   = (const float*)d_in[16];
    float* out = (float*)d_out;

    const int BT = BATCH * T_SEQ;  // 2048
    const int BS = BATCH * KEEP;   // 512

    float* ws = (float*)d_ws;
    size_t o = 0;
    float* XW     = ws + o; o += (size_t)BT * XWW;     // 18.4 MB
    float* QKV    = ws + o; o += (size_t)BT * QKVW;    // 21.0 MB
    float* skv    = ws + o; o += (size_t)BS * SKW;
    float* attn   = ws + o; o += (size_t)BT * 512;
    float* Bxw    = ws + o; o += (size_t)CDIM * XWW;   // 9.2 MB
    float* Bqkv   = ws + o; o += (size_t)128 * QKVW;
    float* Bsel   = ws + o; o += (size_t)CDIM * SKW;   // 8.4 MB
    float2* tab   = (float2*)(ws + o); o += (size_t)T_SEQ * 32 * 2;  // 256 KB
    float* gatef  = ws + o; o += 8;
    int*   idx    = (int*)(ws + o); o += 512;

    auto gemm = [&](const float* A, const float* Bm, float* C, int M, int N, int K,
                    int lda, int ldb, int ldc, int ksplit = 1,
                    const int* Arowidx = nullptr, int rowdiv = 1, int rowmul = 1) {
        int kchunk = (K / ksplit + GBK - 1) / GBK * GBK;  // %16==0
        dim3 grid((N + 127) / 128, (M + 127) / 128, ksplit);
        gemm128<<<grid, 256, 0, stream>>>(A, Bm, C, M, N, K, lda, ldb, ldc, kchunk,
                                          Arowidx, rowdiv, rowmul);
    };

    // packs + rope table + small split-K destination zeroing, one launch
    pack_all<<<2496, 256, 0, stream>>>(Bxw, Bqkv, Bsel, tab, skv, out,
                                       w_cq, w_ckv, w_krope, w_wink, w_winv,
                                       w_imp, w_gate,
                                       w_dqn, w_dqr, w_dkn, w_dv, w_selk, w_selv);

    // GEMM1: everything off x in one wide launch (grid 18x16 = 288, unsplit)
    gemm(x, Bxw, XW, BT, XWW, CDIM, CDIM, XWW, XWW);

    // fused post pass: rms(cq), rms(ckv), rope(kro), rope(wink)
    xw_post<<<BT, 256, 0, stream>>>(XW, g_qnorm, g_kvnorm, tab);

    // gate + topk merged
    topk_gate<<<BATCH, 1024, 0, stream>>>(XW, idx, gatef);

    // GEMM2: QKV = [nq|ckv] @ blockdiag (grid 20x16 = 320, K=128);
    // qr rope deferred to flash staging
    gemm(XW, Bqkv, QKV, BT, QKVW, 128, XWW, QKVW, QKVW);

    // GEMM3: skv = x[idx] @ [w_selk | w_selv] via A-row indirection,
    // split-K 4-way (grid 16x4x4 = 256, small 4MB output); then rope ks
    gemm(x, Bsel, skv, BS, SKW, CDIM, CDIM, SKW, SKW, 4, idx, KEEP, T_SEQ);
    rope_tab<<<512, 256, 0, stream>>>(skv, BS, SKW, 16, 96, 32, KEEP, tab);

    // fused attention (v5 + Q-rope fold)
    dim3 fgrid(T_SEQ / BQ, NHEAD, BATCH);
    flash_fused<<<fgrid, 512, 0, stream>>>(QKV, XW, skv, gatef, tab, attn);

    // output projection, split-K 2-way (grid 8x16x2 = 256, 8MB output)
    gemm(attn, w_proj, out, BT, CDIM, 512, 512, CDIM, CDIM, 2);
}

// Round 16
// 941.664 us; speedup vs baseline: 1.0159x; 1.0159x over previous
//
#include <hip/hip_runtime.h>
#include <math.h>

#define T_SEQ   1024
#define BATCH   2
#define CDIM    1024
#define NHEAD   16
#define VHEAD   32
#define KEEP    256
#define HEAD_D  96   // NOPE + ROPE
#define SCALE_ATTN 0.1020620726159658f  // 1/sqrt(96)

// flash tile params (v5, measured-best: 384 us)
#define BQ   64
#define BKT  64
#define SK   100    // Q/K LDS row stride: 100%32=4 -> <=2-way on b128 (free)
#define SPT  66     // Pt row stride [k][q]: even -> aligned b64 columns
#define SPV  36     // V LDS row stride

// GEMM tile params: 128x128 block, 8x8 micro, single-buffered (spill-safe)
#define GBK 16
#define SA  132     // padded row stride: 132%32=4 -> <=2-way (free)

// XW layout: x @ [cq | ckv | krope | wink | winv | imp | gate]
#define XWW    2244
#define C_CQ   0      // 96
#define C_CKV  96     // 32
#define C_KRO  128    // 64
#define C_WINK 192    // 1536 (16 heads x 96)
#define C_WINV 1728   // 512  (16 heads x 32)
#define C_IMP  2240   // 1
#define C_GATE 2241   // 3

// QKV layout: [nq|ckv] @ blockdiag -> [qn | qr | kn | v1]
#define QKVW   2560
#define C_QN   0      // 512
#define C_QR   512    // 1024 (UN-roped; rope folded into flash Q staging)
#define C_KN   1536   // 512
#define C_V1   2048   // 512

#define SKW  2048   // skv: [0:1536) ks | [1536:2048) vs  (roped by rope_tab)

// ---------------------------------------------------------------------------
// fp32 GEMM v4 (measured-best): C[M,N] = A[M,K] @ B[K,N], strides lda/ldb/ldc.
// 128x128 block, 256 threads, 8x8 micro-tile, single LDS buffer, ~95 VGPR.
// (Round-15 lesson: register-prefetch pipelining is neutral-to-negative —
// compiler scheduling + 4 waves/SIMD already hide staging latency.)
// Split-K via blockIdx.z (gridDim.z>1 -> atomicAdd, C zeroed). Profitable
// ONLY for small outputs (round-13 lesson).
// Optional A-row indirection: Arowidx!=nullptr -> A row gr reads source row
// (gr/rowdiv)*rowmul + Arowidx[gr]  (hoisted to registers before K-loop).
// ---------------------------------------------------------------------------
__global__ __launch_bounds__(256) void gemm128(const float* __restrict__ A,
                                               const float* __restrict__ B,
                                               float* __restrict__ C,
                                               int M, int N, int K,
                                               int lda, int ldb, int ldc,
                                               int kchunk,
                                               const int* __restrict__ Arowidx,
                                               int rowdiv, int rowmul) {
    __shared__ float As[GBK][SA];   // [k][m] transposed A tile
    __shared__ float Bs[GBK][SA];   // [k][n]
    int t = threadIdx.x;
    int tx = t & 15, ty = t >> 4;
    int row0 = blockIdx.y * 128, col0 = blockIdx.x * 128;
    int kb = blockIdx.z * kchunk;
    int ke = min(K, kb + kchunk);
    float acc[8][8] = {};

    // hoist A source rows (fixed across K-steps)
    int asrc[2]; bool aok[2];
#pragma unroll
    for (int r = 0; r < 2; r++) {
        int idx = t + 256 * r;
        int row = idx >> 2;
        int gr = row0 + row;
        aok[r] = (gr < M);
        int ar = gr;
        if (Arowidx != nullptr && aok[r]) ar = (gr / rowdiv) * rowmul + Arowidx[gr];
        asrc[r] = ar;
    }

    for (int k0 = kb; k0 < ke; k0 += GBK) {
#pragma unroll
        for (int r = 0; r < 2; r++) {
            int idx = t + 256 * r;            // 0..511
            int row = idx >> 2, k4 = idx & 3;
            float4 v = make_float4(0.f, 0.f, 0.f, 0.f);
            if (aok[r]) v = *(const float4*)&A[(size_t)asrc[r] * lda + k0 + k4 * 4];
            As[k4 * 4 + 0][row] = v.x;
            As[k4 * 4 + 1][row] = v.y;
            As[k4 * 4 + 2][row] = v.z;
            As[k4 * 4 + 3][row] = v.w;
        }
#pragma unroll
        for (int r = 0; r < 2; r++) {
            int idx = t + 256 * r;
            int kk = idx >> 5, n4 = idx & 31;
            int gc = col0 + n4 * 4;
            float4 v = make_float4(0.f, 0.f, 0.f, 0.f);
            if (gc + 3 < N) {
                v = *(const float4*)&B[(size_t)(k0 + kk) * ldb + gc];
            } else if (gc < N) {
                const float* bp = &B[(size_t)(k0 + kk) * ldb];
                float tmp[4] = {0.f, 0.f, 0.f, 0.f};
                for (int j = 0; j < 4 && gc + j < N; j++) tmp[j] = bp[gc + j];
                v = make_float4(tmp[0], tmp[1], tmp[2], tmp[3]);
            }
            *(float4*)&Bs[kk][n4 * 4] = v;
        }
        __syncthreads();
#pragma unroll
        for (int kk = 0; kk < GBK; kk++) {
            float4 a0 = *(float4*)&As[kk][ty * 4];
            float4 a1 = *(float4*)&As[kk][64 + ty * 4];
            float4 b0 = *(float4*)&Bs[kk][tx * 4];
            float4 b1 = *(float4*)&Bs[kk][64 + tx * 4];
            float av[8] = {a0.x, a0.y, a0.z, a0.w, a1.x, a1.y, a1.z, a1.w};
            float bv[8] = {b0.x, b0.y, b0.z, b0.w, b1.x, b1.y, b1.z, b1.w};
#pragma unroll
            for (int i = 0; i < 8; i++)
#pragma unroll
                for (int j = 0; j < 8; j++) acc[i][j] += av[i] * bv[j];
        }
        __syncthreads();
    }

    bool split = (gridDim.z > 1);
#pragma unroll
    for (int i = 0; i < 8; i++) {
        int gr = row0 + ((i < 4) ? (ty * 4 + i) : (64 + ty * 4 + (i - 4)));
        if (gr >= M) continue;
#pragma unroll
        for (int half = 0; half < 2; half++) {
            int gc = col0 + half * 64 + tx * 4;
            if (gc + 3 >= N) continue;
            float* cp = &C[(size_t)gr * ldc + gc];
            if (split) {
                atomicAdd(cp + 0, acc[i][half * 4 + 0]);
                atomicAdd(cp + 1, acc[i][half * 4 + 1]);
                atomicAdd(cp + 2, acc[i][half * 4 + 2]);
                atomicAdd(cp + 3, acc[i][half * 4 + 3]);
            } else {
                *(float4*)cp = make_float4(acc[i][half * 4 + 0], acc[i][half * 4 + 1],
                                           acc[i][half * 4 + 2], acc[i][half * 4 + 3]);
            }
        }
    }
}

// ---------------------------------------------------------------------------
// merged weight pack + rope table + split-K destination zeroing:
// blocks [0,1024)    -> Bxw rows
//        [1024,1152) -> Bqkv rows
//        [1152,2176) -> Bsel rows
//        [2176,2304) -> tab (cos/sin)
//        [2304,2368) -> zero skv  (split-K dest)
//        [2368,2496) -> zero out  (split-K dest)
__global__ void pack_all(float* __restrict__ Bxw, float* __restrict__ Bqkv,
                         float* __restrict__ Bsel, float2* __restrict__ tab,
                         float* __restrict__ skv, float* __restrict__ outp,
                         const float* __restrict__ cq, const float* __restrict__ ckv,
                         const float* __restrict__ kro, const float* __restrict__ wink,
                         const float* __restrict__ winv, const float* __restrict__ imp,
                         const float* __restrict__ gate,
                         const float* __restrict__ dqn, const float* __restrict__ dqr,
                         const float* __restrict__ dkn, const float* __restrict__ dv,
                         const float* __restrict__ selk, const float* __restrict__ selv) {
    int blk = blockIdx.x;
    if (blk < 1024) {
        int r = blk;
        for (int c = threadIdx.x; c < XWW; c += blockDim.x) {
            float v;
            if      (c < C_CKV)  v = cq  [(size_t)r * 96   + c];
            else if (c < C_KRO)  v = ckv [(size_t)r * 32   + (c - C_CKV)];
            else if (c < C_WINK) v = kro [(size_t)r * 64   + (c - C_KRO)];
            else if (c < C_WINV) v = wink[(size_t)r * 1536 + (c - C_WINK)];
            else if (c < C_IMP)  v = winv[(size_t)r * 512  + (c - C_WINV)];
            else if (c < C_GATE) v = imp [(size_t)r * 1    + (c - C_IMP)];
            else                 v = gate[(size_t)r * 3    + (c - C_GATE)];
            Bxw[(size_t)r * XWW + c] = v;
        }
    } else if (blk < 1152) {
        int r = blk - 1024;
        for (int c = threadIdx.x; c < QKVW; c += blockDim.x) {
            float v = 0.f;
            if (r < 96) {
                if (c < C_QR)      v = dqn[(size_t)r * 512 + c];
                else if (c < C_KN) v = dqr[(size_t)r * 1024 + (c - C_QR)];
            } else {
                if (c >= C_KN && c < C_V1) v = dkn[(size_t)(r - 96) * 512 + (c - C_KN)];
                else if (c >= C_V1)        v = dv [(size_t)(r - 96) * 512 + (c - C_V1)];
            }
            Bqkv[(size_t)r * QKVW + c] = v;
        }
    } else if (blk < 2176) {
        int r = blk - 1152;
        for (int c = threadIdx.x; c < SKW; c += blockDim.x) {
            float v = (c < 1536) ? selk[(size_t)r * 1536 + c]
                                 : selv[(size_t)r * 512 + (c - 1536)];
            Bsel[(size_t)r * SKW + c] = v;
        }
    } else if (blk < 2304) {
        int idx = (blk - 2176) * 256 + threadIdx.x;   // 128 x 256 = 32768
        if (idx < T_SEQ * 32) {
            int pos = idx >> 5, i = idx & 31;
            float expo = (float)i * (1.0f / 32.0f);
            float f = 1.0f / powf(10000.0f, expo);
            float a = (float)pos * f;
            float s, c;
            sincosf(a, &s, &c);
            tab[idx] = make_float2(c, s);
        }
    } else if (blk < 2368) {
        // zero skv: 512*2048 floats = 262,144 float4 (64 blocks x 256 x 16)
        size_t base = (size_t)(blk - 2304) * 256 + threadIdx.x;
#pragma unroll
        for (int j = 0; j < 16; j++)
            ((float4*)skv)[base + (size_t)j * 16384] = make_float4(0.f, 0.f, 0.f, 0.f);
    } else {
        // zero out: 2048*1024 floats = 524,288 float4 (128 blocks x 256 x 16)
        size_t base = (size_t)(blk - 2368) * 256 + threadIdx.x;
#pragma unroll
        for (int j = 0; j < 16; j++)
            ((float4*)outp)[base + (size_t)j * 32768] = make_float4(0.f, 0.f, 0.f, 0.f);
    }
}

// ---------------------------------------------------------------------------
// fused post-XW row pass: rms(cq), rms(ckv), rope(kro, scale 1/16),
// rope(wink heads). One block per row, 256 threads; disjoint slices.
__global__ void xw_post(float* __restrict__ XW, const float* __restrict__ gq,
                        const float* __restrict__ gkv,
                        const float2* __restrict__ tab) {
    int row = blockIdx.x;
    int t = threadIdx.x;
    int w = t >> 6, lane = t & 63;
    float* rp = XW + (size_t)row * XWW;
    int pos = row & (T_SEQ - 1);
    const float2* tp = tab + pos * 32;

    if (w == 0) {                      // rms over cols [0,96)
        float ss = 0.f;
        for (int d = lane; d < 96; d += 64) { float v = rp[d]; ss += v * v; }
        for (int off = 32; off; off >>= 1) ss += __shfl_xor(ss, off, 64);
        float r = rsqrtf(ss / 96.0f + 1e-6f);
        for (int d = lane; d < 96; d += 64) rp[d] *= r * gq[d];
    } else if (w == 1) {               // rms over cols [96,128)
        float ss = 0.f;
        for (int d = lane; d < 32; d += 64) { float v = rp[C_CKV + d]; ss += v * v; }
        for (int off = 32; off; off >>= 1) ss += __shfl_xor(ss, off, 64);
        float r = rsqrtf(ss / 32.0f + 1e-6f);
        for (int d = lane; d < 32; d += 64) rp[C_CKV + d] *= r * gkv[d];
    } else if (w == 2) {               // rope kro cols [128,192), scale 1/16
        if (lane < 32) {
            float2 cs = tp[lane];
            float v1 = rp[C_KRO + lane], v2 = rp[C_KRO + 32 + lane];
            rp[C_KRO + lane]      = (v1 * cs.x - v2 * cs.y) * (1.0f / NHEAD);
            rp[C_KRO + 32 + lane] = (v1 * cs.y + v2 * cs.x) * (1.0f / NHEAD);
        }
    }
    // wink rope: 16 heads x 32 items, all 256 threads, 2 items each
#pragma unroll
    for (int j = 0; j < 2; j++) {
        int item = t + j * 256;        // 0..511
        int h = item >> 5, i = item & 31;
        float2 cs = tp[i];
        size_t base = (size_t)(C_WINK + 32) + h * 96;
        float v1 = rp[base + i], v2 = rp[base + 32 + i];
        rp[base + i]      = v1 * cs.x - v2 * cs.y;
        rp[base + 32 + i] = v1 * cs.y + v2 * cs.x;
    }
}

// ---------------------------------------------------------------------------
// table-based rope
__global__ void rope_tab(float* __restrict__ buf, int nrows, int rstride,
                         int nheads, int hstride, int roff, int posmod,
                         const float2* __restrict__ tab) {
    int total = nrows * nheads * 32;
    for (int it = blockIdx.x * blockDim.x + threadIdx.x; it < total;
         it += gridDim.x * blockDim.x) {
        int i = it & 31;
        int hr = it >> 5;
        int h = hr % nheads;
        int row = hr / nheads;
        int pos = row % posmod;
        float2 cs = tab[pos * 32 + i];
        size_t base = (size_t)row * rstride + (size_t)h * hstride + roff;
        float v1 = buf[base + i], v2 = buf[base + 32 + i];
        buf[base + i]      = v1 * cs.x - v2 * cs.y;
        buf[base + 32 + i] = v1 * cs.y + v2 * cs.x;
    }
}

// ---------------------------------------------------------------------------
// merged gate softmax + top-k over XW columns; grid = BATCH, 1024 threads
__global__ void topk_gate(const float* __restrict__ xw, int* __restrict__ idx,
                          float* __restrict__ gate) {
    int b = blockIdx.x;
    __shared__ float s[1024];
    __shared__ int ps[1024];
    __shared__ float gred[3][16];
    int t = threadIdx.x;
    const float* rowp = &xw[((size_t)b * T_SEQ + t) * XWW];
    s[t] = rowp[C_IMP];
    float g0 = rowp[C_GATE + 0], g1 = rowp[C_GATE + 1], g2 = rowp[C_GATE + 2];
    for (int off = 32; off; off >>= 1) {
        g0 += __shfl_xor(g0, off, 64);
        g1 += __shfl_xor(g1, off, 64);
        g2 += __shfl_xor(g2, off, 64);
    }
    if ((t & 63) == 0) { int w = t >> 6; gred[0][w] = g0; gred[1][w] = g1; gred[2][w] = g2; }
    __syncthreads();
    if (t == 0) {
        float v0 = 0.f, v1 = 0.f, v2 = 0.f;
        for (int w = 0; w < 16; w++) { v0 += gred[0][w]; v1 += gred[1][w]; v2 += gred[2][w]; }
        v0 /= (float)T_SEQ; v1 /= (float)T_SEQ; v2 /= (float)T_SEQ;
        float m = fmaxf(v0, fmaxf(v1, v2));
        float e0 = expf(v0 - m), e1 = expf(v1 - m), e2 = expf(v2 - m);
        float ssum = e0 + e1 + e2;
        gate[b * 3 + 0] = e0 / ssum;
        gate[b * 3 + 1] = e1 / ssum;
        gate[b * 3 + 2] = e2 / ssum;
    }
    __syncthreads();
    float mine = s[t];
    int rank = 0;
    for (int j = 0; j < 1024; j++) {
        float v = s[j];
        rank += (v > mine) || (v == mine && j < t);
    }
    int selv = (rank < KEEP) ? 1 : 0;
    ps[t] = selv;
    __syncthreads();
    for (int off = 1; off < 1024; off <<= 1) {
        int add = (t >= off) ? ps[t - off] : 0;
        __syncthreads();
        ps[t] += add;
        __syncthreads();
    }
    if (selv) idx[b * KEEP + ps[t] - 1] = t;
}

// ---------------------------------------------------------------------------
// Fused 3-branch flash attention v5 (measured-best) + Q-rope fold
// (once per (row,head), staged by exactly one block).
// Register-resident online softmax; 2 barriers per tile.
// Grid: (T/64, NHEAD, BATCH), 512 threads. LDS 77.3 KB -> 2 blocks/CU.
// ---------------------------------------------------------------------------
__global__ __launch_bounds__(512, 4) void flash_fused(
    const float* __restrict__ qkv, const float* __restrict__ xw,
    const float* __restrict__ skv, const float* __restrict__ gate,
    const float2* __restrict__ tab, float* __restrict__ out) {
    __shared__ float Qs[BQ * SK];
    __shared__ float Ks[BKT * SK];
    __shared__ float Vs[BKT * SPV];
    __shared__ float Pt[BKT * SPT];

    int b = blockIdx.z, h = blockIdx.y;
    int qt = blockIdx.x;
    if (b == 1) qt = (gridDim.x - 1) - qt;   // balance causal cost across z-pairs
    int q0 = qt * BQ;
    int t = threadIdx.x;
    int tq = t >> 4, tk = t & 15;   // S: q=2*tq+i, k=16*j+tk; PV: q=2*tq+i, d=2*tk+j

    // stage Q tile (64 rows x 24 float4); qr rope applied on the fly
    for (int i = t; i < BQ * 24; i += 512) {
        int row = i / 24, d4 = i % 24;
        size_t rq = (size_t)b * T_SEQ + q0 + row;
        float4 v;
        if (d4 < 8) {
            v = *(const float4*)&qkv[rq * QKVW + C_QN + h * 32 + d4 * 4];
        } else {
            const float* qb = &qkv[rq * QKVW + C_QR + h * 64];
            int dd = d4 - 8;                  // 0..15 within 64-wide head slice
            float4 a = *(const float4*)&qb[dd * 4];
            const float2* tp = tab + (size_t)(q0 + row) * 32;
            if (dd < 8) {                     // first half: v1*c - v2*s
                float4 p = *(const float4*)&qb[(dd + 8) * 4];
                int i0 = dd * 4;
                float2 c0 = tp[i0], c1 = tp[i0 + 1], c2 = tp[i0 + 2], c3 = tp[i0 + 3];
                v = make_float4(a.x * c0.x - p.x * c0.y, a.y * c1.x - p.y * c1.y,
                                a.z * c2.x - p.z * c2.y, a.w * c3.x - p.w * c3.y);
            } else {                          // second half: v1*s + v2*c
                float4 p = *(const float4*)&qb[(dd - 8) * 4];
                int i0 = (dd - 8) * 4;
                float2 c0 = tp[i0], c1 = tp[i0 + 1], c2 = tp[i0 + 2], c3 = tp[i0 + 3];
                v = make_float4(p.x * c0.y + a.x * c0.x, p.y * c1.y + a.y * c1.x,
                                p.z * c2.y + a.z * c2.x, p.w * c3.y + a.w * c3.x);
            }
        }
        *(float4*)&Qs[row * SK + d4 * 4] = v;
    }

    int qq0 = q0 + 2 * tq, qq1 = qq0 + 1;
    float comb[2][2] = {};
    for (int phase = 0; phase < 3; phase++) {
        bool causal = (phase != 1);
        int ntiles = causal ? (qt + 1) : (KEEP / BKT);
        float m0 = -1e30f, m1 = -1e30f, l0 = 0.f, l1 = 0.f;
        float o00 = 0.f, o01 = 0.f, o10 = 0.f, o11 = 0.f;

        for (int kt = 0; kt < ntiles; kt++) {
            int j0 = kt * BKT;
            __syncthreads();  // all waves done reading Ks/Vs of prev tile (covers Qs 1st time)

            // stage K tile (64 rows x 24 float4)
            for (int i = t; i < BKT * 24; i += 512) {
                int row = i / 24, d4 = i % 24;
                int j = j0 + row;
                float4 v;
                if (phase == 0) {
                    size_t rk = (size_t)b * T_SEQ + j;
                    if (d4 < 8) v = *(const float4*)&qkv[rk * QKVW + C_KN + h * 32 + d4 * 4];
                    else        v = *(const float4*)&xw[rk * XWW + C_KRO + (d4 - 8) * 4];
                } else if (phase == 1) {
                    v = *(const float4*)&skv[((size_t)b * KEEP + j) * SKW + h * 96 + d4 * 4];
                } else {
                    v = *(const float4*)&xw[((size_t)b * T_SEQ + j) * XWW + C_WINK + h * 96 + d4 * 4];
                }
                *(float4*)&Ks[row * SK + d4 * 4] = v;
            }
            // stage V tile (64 rows x 8 float4)
            for (int i = t; i < BKT * 8; i += 512) {
                int row = i >> 3, d4 = i & 7;
                int j = j0 + row;
                float4 v;
                if (phase == 0)      v = *(const float4*)&qkv[((size_t)b * T_SEQ + j) * QKVW + C_V1 + h * 32 + d4 * 4];
                else if (phase == 1) v = *(const float4*)&skv[((size_t)b * KEEP  + j) * SKW + 1536 + h * 32 + d4 * 4];
                else                 v = *(const float4*)&xw[((size_t)b * T_SEQ + j) * XWW + C_WINV + h * 32 + d4 * 4];
                *(float4*)&Vs[row * SPV + d4 * 4] = v;
            }
            __syncthreads();

            // S = Q.K^T (2q x 4k per thread), registers
            float s0[4] = {}, s1[4] = {};
#pragma unroll 6
            for (int d = 0; d < HEAD_D; d += 4) {
                float4 qa = *(float4*)&Qs[(2 * tq)     * SK + d];
                float4 qb = *(float4*)&Qs[(2 * tq + 1) * SK + d];
#pragma unroll
                for (int j = 0; j < 4; j++) {
                    float4 kv = *(float4*)&Ks[(16 * j + tk) * SK + d];
                    s0[j] += qa.x * kv.x + qa.y * kv.y + qa.z * kv.z + qa.w * kv.w;
                    s1[j] += qb.x * kv.x + qb.y * kv.y + qb.z * kv.z + qb.w * kv.w;
                }
            }
            // scale + mask + tile row-max (in-reg + 4-shfl over 16-lane group)
            float mt0 = -1e30f, mt1 = -1e30f;
#pragma unroll
            for (int j = 0; j < 4; j++) {
                int kk = j0 + 16 * j + tk;
                s0[j] *= SCALE_ATTN;
                s1[j] *= SCALE_ATTN;
                if (causal && kk > qq0) s0[j] = -1e30f;
                if (causal && kk > qq1) s1[j] = -1e30f;
                mt0 = fmaxf(mt0, s0[j]);
                mt1 = fmaxf(mt1, s1[j]);
            }
#pragma unroll
            for (int off = 1; off <= 8; off <<= 1) {
                mt0 = fmaxf(mt0, __shfl_xor(mt0, off, 64));
                mt1 = fmaxf(mt1, __shfl_xor(mt1, off, 64));
            }
            float mn0 = fmaxf(m0, mt0), mn1 = fmaxf(m1, mt1);
            float a0 = __expf(m0 - mn0), a1 = __expf(m1 - mn1);
            m0 = mn0; m1 = mn1;

            // exponentiate in regs, write P once (float2), row-sum via shfl
            float rs0 = 0.f, rs1 = 0.f;
#pragma unroll
            for (int j = 0; j < 4; j++) {
                float p0 = __expf(s0[j] - mn0);
                float p1 = __expf(s1[j] - mn1);
                rs0 += p0; rs1 += p1;
                *(float2*)&Pt[(16 * j + tk) * SPT + 2 * tq] = make_float2(p0, p1);
            }
#pragma unroll
            for (int off = 1; off <= 8; off <<= 1) {
                rs0 += __shfl_xor(rs0, off, 64);
                rs1 += __shfl_xor(rs1, off, 64);
            }
            l0 = l0 * a0 + rs0;
            l1 = l1 * a1 + rs1;

            // PV (2q x 2d). Pt cols 2tq,2tq+1 written by this same wave ->
            // DS in-order per wave, no barrier.
            o00 *= a0; o01 *= a0; o10 *= a1; o11 *= a1;
#pragma unroll 8
            for (int kk = 0; kk < BKT; kk++) {
                float2 pv = *(float2*)&Pt[kk * SPT + 2 * tq];
                float2 vv = *(float2*)&Vs[kk * SPV + 2 * tk];
                o00 += pv.x * vv.x; o01 += pv.x * vv.y;
                o10 += pv.y * vv.x; o11 += pv.y * vv.y;
            }
        }  // key tiles

        // gate combine (m,l in registers, replicated within the group)
        float g = gate[b * 3 + phase];
        float i0 = g / l0, i1 = g / l1;
        comb[0][0] += o00 * i0; comb[0][1] += o01 * i0;
        comb[1][0] += o10 * i1; comb[1][1] += o11 * i1;
    }  // phases

    size_t r0 = ((size_t)b * T_SEQ + q0 + 2 * tq) * 512 + h * 32 + 2 * tk;
    out[r0]           = comb[0][0];
    out[r0 + 1]       = comb[0][1];
    out[r0 + 512]     = comb[1][0];
    out[r0 + 512 + 1] = comb[1][1];
}

// ---------------------------------------------------------------------------
extern "C" void kernel_launch(void* const* d_in, const int* in_sizes, int n_in,
                              void* d_out, int out_size, void* d_ws, size_t ws_size,
                              hipStream_t stream) {
    const float* x        = (const float*)d_in[0];
    const float* w_cq     = (const float*)d_in[1];
    const float* g_qnorm  = (const float*)d_in[2];
    const float* w_dqn    = (const float*)d_in[3];
    const float* w_dqr    = (const float*)d_in[4];
    const float* w_ckv    = (const float*)d_in[5];
    const float* g_kvnorm = (const float*)d_in[6];
    const float* w_dkn    = (const float*)d_in[7];
    const float* w_dv     = (const float*)d_in[8];
    const float* w_krope  = (const float*)d_in[9];
    const float* w_imp    = (const float*)d_in[10];
    const float* w_selk   = (const float*)d_in[11];
    const float* w_selv   = (const float*)d_in[12];
    const float* w_wink   = (const float*)d_in[13];
    const float* w_winv   = (const float*)d_in[14];
    const float* w_gate   = (const float*)d_in[15];
    const float* w_proj   = (const float*)d_in[16];
    float* out = (float*)d_out;

    const int BT = BATCH * T_SEQ;  // 2048
    const int BS = BATCH * KEEP;   // 512

    float* ws = (float*)d_ws;
    size_t o = 0;
    float* XW     = ws + o; o += (size_t)BT * XWW;     // 18.4 MB
    float* QKV    = ws + o; o += (size_t)BT * QKVW;    // 21.0 MB
    float* skv    = ws + o; o += (size_t)BS * SKW;
    float* attn   = ws + o; o += (size_t)BT * 512;
    float* Bxw    = ws + o; o += (size_t)CDIM * XWW;   // 9.2 MB
    float* Bqkv   = ws + o; o += (size_t)128 * QKVW;
    float* Bsel   = ws + o; o += (size_t)CDIM * SKW;   // 8.4 MB
    float2* tab   = (float2*)(ws + o); o += (size_t)T_SEQ * 32 * 2;  // 256 KB
    float* gatef  = ws + o; o += 8;
    int*   idx    = (int*)(ws + o); o += 512;

    auto gemm = [&](const float* A, const float* Bm, float* C, int M, int N, int K,
                    int lda, int ldb, int ldc, int ksplit = 1,
                    const int* Arowidx = nullptr, int rowdiv = 1, int rowmul = 1) {
        int kchunk = (K / ksplit + GBK - 1) / GBK * GBK;  // %16==0
        dim3 grid((N + 127) / 128, (M + 127) / 128, ksplit);
        gemm128<<<grid, 256, 0, stream>>>(A, Bm, C, M, N, K, lda, ldb, ldc, kchunk,
                                          Arowidx, rowdiv, rowmul);
    };

    // packs + rope table + small split-K destination zeroing, one launch
    pack_all<<<2496, 256, 0, stream>>>(Bxw, Bqkv, Bsel, tab, skv, out,
                                       w_cq, w_ckv, w_krope, w_wink, w_winv,
                                       w_imp, w_gate,
                                       w_dqn, w_dqr, w_dkn, w_dv, w_selk, w_selv);

    // GEMM1: everything off x in one wide launch (grid 18x16 = 288, unsplit)
    gemm(x, Bxw, XW, BT, XWW, CDIM, CDIM, XWW, XWW);

    // fused post pass: rms(cq), rms(ckv), rope(kro), rope(wink)
    xw_post<<<BT, 256, 0, stream>>>(XW, g_qnorm, g_kvnorm, tab);

    // gate + topk merged
    topk_gate<<<BATCH, 1024, 0, stream>>>(XW, idx, gatef);

    // GEMM2: QKV = [nq|ckv] @ blockdiag (grid 20x16 = 320, K=128);
    // qr rope deferred to flash staging
    gemm(XW, Bqkv, QKV, BT, QKVW, 128, XWW, QKVW, QKVW);

    // GEMM3: skv = x[idx] @ [w_selk | w_selv] via A-row indirection,
    // split-K 4-way (grid 16x4x4 = 256, small 4MB output); then rope ks
    gemm(x, Bsel, skv, BS, SKW, CDIM, CDIM, SKW, SKW, 4, idx, KEEP, T_SEQ);
    rope_tab<<<512, 256, 0, stream>>>(skv, BS, SKW, 16, 96, 32, KEEP, tab);

    // fused attention (v5 + Q-rope fold)
    dim3 fgrid(T_SEQ / BQ, NHEAD, BATCH);
    flash_fused<<<fgrid, 512, 0, stream>>>(QKV, XW, skv, gatef, tab, attn);

    // output projection, split-K 2-way (grid 8x16x2 = 256, 8MB output)
    gemm(attn, w_proj, out, BT, CDIM, 512, 512, CDIM, CDIM, 2);
}